// Round 3
// baseline (197.688 us; speedup 1.0000x reference)
//
#include <hip/hip_runtime.h>
#include <math.h>

// Router: logits = X @ W^T + b ; top-2 over 64 experts; softmax over the 2; rest 0.
// X: [32768, 1024] fp32, W: [64, 1024] fp32, b: [64] fp32, Out: [32768, 64] fp32.
//
// 512 blocks x 512 threads (8 waves). Each block: 64 tokens, all 64 experts.
// Split-K: wave q handles d in [q*128, (q+1)*128), wave-private LDS tiles,
// zero barriers in the main loop. Per-lane 8x8 register tile:
// token = i*8 + tg (tg = lane>>3), expert = eg*8 + j (eg = lane&7).
// Reduction: symmetric 2-round all-wave tree through LDS scratch aliased
// over the staging buffers; each wave finalizes 4 tokens per round with a
// 16-lane butterfly top-2 (lex order == jax top_k tie semantics).

#define TPB 64           // tokens per block
#define DK  16           // d-chunk per staging iteration
#define DPW 128          // d per wave (1024/8)
#define NCHUNK (DPW / DK)

__launch_bounds__(512, 4)
__global__ void router_kernel(const float* __restrict__ X,
                              const float* __restrict__ W,
                              const float* __restrict__ Bv,
                              float* __restrict__ Out)
{
    // Staging tiles (main loop) aliased with reduction scratch (after barrier).
    // sIn: 8*64*17 = 8704 floats, sW: 8704 floats, total 17408 floats (69632 B).
    // sScr: 8*32*65 = 16640 floats <= 17408. OK.
    __shared__ __align__(16) float smemF[2 * 8 * 64 * (DK + 1)];
    float (*sIn)[64][DK + 1] = (float (*)[64][DK + 1])smemF;
    float (*sW )[64][DK + 1] = (float (*)[64][DK + 1])(smemF + 8 * 64 * (DK + 1));
    float (*sScr)[32][65]    = (float (*)[32][65])smemF;
    __shared__ float sB[64];
    __shared__ float rW1[TPB], rW2[TPB];
    __shared__ int   rI1[TPB], rI2[TPB];

    const int tid  = threadIdx.x;
    const int q    = tid >> 6;       // wave id = K-slice
    const int lane = tid & 63;
    const int tg   = lane >> 3;      // token sub-index
    const int eg   = lane & 7;       // expert group (8 experts)
    const int tokBase = blockIdx.x * TPB;

    if (tid < 64) sB[tid] = Bv[tid];

    // Staging roles: lane -> (row st = lane>>2 in 0..15, float4 col sc = lane&3)
    const int st = lane >> 2;
    const int sc = lane & 3;
    const int dq0 = q * DPW;

    const float* pIn = X + (size_t)(tokBase + st) * 1024 + dq0 + sc * 4;
    const float* pW  = W + (size_t)st * 1024 + dq0 + sc * 4;

    float acc[8][8];
    #pragma unroll
    for (int i = 0; i < 8; ++i)
        #pragma unroll
        for (int j = 0; j < 8; ++j) acc[i][j] = 0.f;

    float4 bufA[8], bufB[8];

    auto LOAD = [&](int c, float4* buf) {
        const int off = c * DK;
        #pragma unroll
        for (int k = 0; k < 4; ++k) {
            buf[k]     = *(const float4*)(pIn + (size_t)k * 16 * 1024 + off);
            buf[4 + k] = *(const float4*)(pW  + (size_t)k * 16 * 1024 + off);
        }
    };
    auto STORE = [&](const float4* buf) {
        #pragma unroll
        for (int k = 0; k < 4; ++k) {
            const int r = st + k * 16;
            sIn[q][r][sc * 4 + 0] = buf[k].x;
            sIn[q][r][sc * 4 + 1] = buf[k].y;
            sIn[q][r][sc * 4 + 2] = buf[k].z;
            sIn[q][r][sc * 4 + 3] = buf[k].w;
            sW [q][r][sc * 4 + 0] = buf[4 + k].x;
            sW [q][r][sc * 4 + 1] = buf[4 + k].y;
            sW [q][r][sc * 4 + 2] = buf[4 + k].z;
            sW [q][r][sc * 4 + 3] = buf[4 + k].w;
        }
    };
    auto COMPUTE = [&]() {
        #pragma unroll 4
        for (int dd = 0; dd < DK; ++dd) {
            float av[8], wv[8];
            #pragma unroll
            for (int i = 0; i < 8; ++i) av[i] = sIn[q][i * 8 + tg][dd];
            #pragma unroll
            for (int j = 0; j < 8; ++j) wv[j] = sW[q][eg * 8 + j][dd];
            #pragma unroll
            for (int i = 0; i < 8; ++i)
                #pragma unroll
                for (int j = 0; j < 8; ++j)
                    acc[i][j] = fmaf(av[i], wv[j], acc[i][j]);
        }
    };

    // Main loop: wave-private LDS tiles, manual 2-chunk pipeline, no barriers.
    LOAD(0, bufA);
    #pragma unroll 1
    for (int c = 0; c < NCHUNK; c += 2) {
        STORE(bufA);
        if (c + 1 < NCHUNK) LOAD(c + 1, bufB);
        COMPUTE();
        STORE(bufB);
        if (c + 2 < NCHUNK) LOAD(c + 2, bufA);
        COMPUTE();
    }

    // ---- Symmetric all-wave reduction + top-2, 2 rounds of 32 tokens ----
    const int lw = lane >> 4;    // 0..3: token sub within wave's finalize set
    const int le = lane & 15;    // 0..15: expert quad id
    const int e0 = le * 4;

    __syncthreads();             // all waves done with sIn/sW (alias hazard)

    #pragma unroll
    for (int r = 0; r < 2; ++r) {
        if (r) __syncthreads();  // prior round's reads done before overwrite

        // Every wave writes its partials for tokens [32r, 32r+32).
        #pragma unroll
        for (int i = 0; i < 4; ++i)
            #pragma unroll
            for (int j = 0; j < 8; ++j)
                sScr[q][i * 8 + tg][eg * 8 + j] = acc[4 * r + i][j];
        __syncthreads();

        // Wave q finalizes tokens 32r + 4q + lw.
        const int tl = 4 * q + lw;
        float v[4];
        #pragma unroll
        for (int j = 0; j < 4; ++j) v[j] = sB[e0 + j];
        #pragma unroll
        for (int p = 0; p < 8; ++p)
            #pragma unroll
            for (int j = 0; j < 4; ++j)
                v[j] += sScr[p][tl][e0 + j];

        // In-lane top-2 over 4 experts.
        float v1 = -INFINITY, v2 = -INFINITY;
        int i1 = 0, i2 = 0;
        #pragma unroll
        for (int j = 0; j < 4; ++j) {
            const float val = v[j];
            const int   e   = e0 + j;
            if (val > v1)      { v2 = v1; i2 = i1; v1 = val; i1 = e; }
            else if (val > v2) { v2 = val; i2 = e; }
        }
        // Butterfly merge across the 16 lanes of this token
        // (lex order: value desc, index asc == jax top_k tie semantics).
        #pragma unroll
        for (int s = 1; s <= 8; s <<= 1) {
            const float o1 = __shfl_xor(v1, s);
            const int  oi1 = __shfl_xor(i1, s);
            const float o2 = __shfl_xor(v2, s);
            const int  oi2 = __shfl_xor(i2, s);
            const bool b1 = (o1 > v1) || (o1 == v1 && oi1 < i1);
            if (b1) {
                const bool b2 = (v1 > o2) || (v1 == o2 && i1 < oi2);
                v2 = b2 ? v1 : o2;  i2 = b2 ? i1 : oi2;
                v1 = o1;            i1 = oi1;
            } else {
                const bool b2 = (o1 > v2) || (o1 == v2 && oi1 < i2);
                if (b2) { v2 = o1; i2 = oi1; }
            }
        }
        if (le == 0) {
            const int t = 32 * r + tl;
            const float ex = expf(v2 - v1);        // <= 1
            const float w1 = 1.f / (1.f + ex);
            rI1[t] = i1;  rI2[t] = i2;
            rW1[t] = w1;  rW2[t] = ex * w1;
        }
    }
    __syncthreads();

    // ---- Coalesced output: 64 tokens x 64 floats = 1024 float4, contiguous ----
    float4* O4 = (float4*)(Out + (size_t)tokBase * 64);
    #pragma unroll
    for (int idx = tid; idx < TPB * 64 / 4; idx += 512) {
        const int t  = idx >> 4;
        const int c0 = (idx & 15) << 2;
        const int i1 = rI1[t], i2 = rI2[t];
        const float w1 = rW1[t], w2 = rW2[t];
        float4 o;
        o.x = (c0 + 0 == i1) ? w1 : ((c0 + 0 == i2) ? w2 : 0.f);
        o.y = (c0 + 1 == i1) ? w1 : ((c0 + 1 == i2) ? w2 : 0.f);
        o.z = (c0 + 2 == i1) ? w1 : ((c0 + 2 == i2) ? w2 : 0.f);
        o.w = (c0 + 3 == i1) ? w1 : ((c0 + 3 == i2) ? w2 : 0.f);
        O4[idx] = o;
    }
}

extern "C" void kernel_launch(void* const* d_in, const int* in_sizes, int n_in,
                              void* d_out, int out_size, void* d_ws, size_t ws_size,
                              hipStream_t stream) {
    const float* X  = (const float*)d_in[0];   // [32768, 1024]
    const float* Wt = (const float*)d_in[1];   // [64, 1024]
    const float* Bv = (const float*)d_in[2];   // [64]
    float* Out = (float*)d_out;                // [32768, 64]

    const int tokens = 8 * 4096;               // 32768
    dim3 grid(tokens / TPB);                   // 512 blocks
    dim3 block(512);
    hipLaunchKernelGGL(router_kernel, grid, block, 0, stream, X, Wt, Bv, Out);
}

// Round 4
// 80.301 us; speedup vs baseline: 2.4618x; 2.4618x over previous
//
#include <hip/hip_runtime.h>
#include <math.h>

// Router: logits = X @ W^T + b ; top-2 over 64 experts; softmax over the 2; rest 0.
// X: [32768, 1024] fp32, W: [64, 1024] fp32, b: [64] fp32, Out: [32768, 64] fp32.
//
// 512 blocks x 512 threads (8 waves). Each block: 64 tokens, all 64 experts.
// Split-K: wave q handles d in [q*128, (q+1)*128), wave-private LDS tiles,
// zero barriers in the main loop. Per-lane 8x8 register tile:
// token = i*8 + tg (tg = lane>>3), expert = eg*8 + j (eg = lane&7).
// Reduction: symmetric 2-round all-wave tree through LDS scratch aliased
// over the staging buffers; each wave finalizes 4 tokens per round with a
// 16-lane butterfly top-2 (lex order == jax top_k tie semantics).
//
// launch_bounds: (512, 2) NOT (512, 4) — the 4-waves/EU variant capped the
// allocator at 64 VGPRs and spilled acc[8][8] to scratch (WRITE_SIZE 8MB ->
// 330MB, 2.3x slowdown). 128-VGPR cap fits the ~120 this structure needs;
// occupancy is then LDS-limited at 2 blocks/CU x 8 waves = 50%.

#define TPB 64           // tokens per block
#define DK  16           // d-chunk per staging iteration
#define DPW 128          // d per wave (1024/8)
#define NCHUNK (DPW / DK)

__launch_bounds__(512, 2)
__global__ void router_kernel(const float* __restrict__ X,
                              const float* __restrict__ W,
                              const float* __restrict__ Bv,
                              float* __restrict__ Out)
{
    // Staging tiles (main loop) aliased with reduction scratch (after barrier).
    // sIn: 8*64*17 = 8704 floats, sW: 8704 floats, total 17408 floats (69632 B).
    // sScr: 8*32*65 = 16640 floats <= 17408. OK.
    __shared__ __align__(16) float smemF[2 * 8 * 64 * (DK + 1)];
    float (*sIn)[64][DK + 1] = (float (*)[64][DK + 1])smemF;
    float (*sW )[64][DK + 1] = (float (*)[64][DK + 1])(smemF + 8 * 64 * (DK + 1));
    float (*sScr)[32][65]    = (float (*)[32][65])smemF;
    __shared__ float sB[64];
    __shared__ float rW1[TPB], rW2[TPB];
    __shared__ int   rI1[TPB], rI2[TPB];

    const int tid  = threadIdx.x;
    const int q    = tid >> 6;       // wave id = K-slice
    const int lane = tid & 63;
    const int tg   = lane >> 3;      // token sub-index
    const int eg   = lane & 7;       // expert group (8 experts)
    const int tokBase = blockIdx.x * TPB;

    if (tid < 64) sB[tid] = Bv[tid];

    // Staging roles: lane -> (row st = lane>>2 in 0..15, float4 col sc = lane&3)
    const int st = lane >> 2;
    const int sc = lane & 3;
    const int dq0 = q * DPW;

    const float* pIn = X + (size_t)(tokBase + st) * 1024 + dq0 + sc * 4;
    const float* pW  = W + (size_t)st * 1024 + dq0 + sc * 4;

    float acc[8][8];
    #pragma unroll
    for (int i = 0; i < 8; ++i)
        #pragma unroll
        for (int j = 0; j < 8; ++j) acc[i][j] = 0.f;

    float4 bufA[8], bufB[8];

    auto LOAD = [&](int c, float4* buf) {
        const int off = c * DK;
        #pragma unroll
        for (int k = 0; k < 4; ++k) {
            buf[k]     = *(const float4*)(pIn + (size_t)k * 16 * 1024 + off);
            buf[4 + k] = *(const float4*)(pW  + (size_t)k * 16 * 1024 + off);
        }
    };
    auto STORE = [&](const float4* buf) {
        #pragma unroll
        for (int k = 0; k < 4; ++k) {
            const int r = st + k * 16;
            sIn[q][r][sc * 4 + 0] = buf[k].x;
            sIn[q][r][sc * 4 + 1] = buf[k].y;
            sIn[q][r][sc * 4 + 2] = buf[k].z;
            sIn[q][r][sc * 4 + 3] = buf[k].w;
            sW [q][r][sc * 4 + 0] = buf[4 + k].x;
            sW [q][r][sc * 4 + 1] = buf[4 + k].y;
            sW [q][r][sc * 4 + 2] = buf[4 + k].z;
            sW [q][r][sc * 4 + 3] = buf[4 + k].w;
        }
    };
    auto COMPUTE = [&]() {
        #pragma unroll 4
        for (int dd = 0; dd < DK; ++dd) {
            float av[8], wv[8];
            #pragma unroll
            for (int i = 0; i < 8; ++i) av[i] = sIn[q][i * 8 + tg][dd];
            #pragma unroll
            for (int j = 0; j < 8; ++j) wv[j] = sW[q][eg * 8 + j][dd];
            #pragma unroll
            for (int i = 0; i < 8; ++i)
                #pragma unroll
                for (int j = 0; j < 8; ++j)
                    acc[i][j] = fmaf(av[i], wv[j], acc[i][j]);
        }
    };

    // Main loop: wave-private LDS tiles, manual 2-chunk pipeline, no barriers.
    LOAD(0, bufA);
    #pragma unroll 1
    for (int c = 0; c < NCHUNK; c += 2) {
        STORE(bufA);
        if (c + 1 < NCHUNK) LOAD(c + 1, bufB);
        COMPUTE();
        STORE(bufB);
        if (c + 2 < NCHUNK) LOAD(c + 2, bufA);
        COMPUTE();
    }

    // ---- Symmetric all-wave reduction + top-2, 2 rounds of 32 tokens ----
    const int lw = lane >> 4;    // 0..3: token sub within wave's finalize set
    const int le = lane & 15;    // 0..15: expert quad id
    const int e0 = le * 4;

    __syncthreads();             // all waves done with sIn/sW (alias hazard)

    #pragma unroll
    for (int r = 0; r < 2; ++r) {
        if (r) __syncthreads();  // prior round's reads done before overwrite

        // Every wave writes its partials for tokens [32r, 32r+32).
        #pragma unroll
        for (int i = 0; i < 4; ++i)
            #pragma unroll
            for (int j = 0; j < 8; ++j)
                sScr[q][i * 8 + tg][eg * 8 + j] = acc[4 * r + i][j];
        __syncthreads();

        // Wave q finalizes tokens 32r + 4q + lw.
        const int tl = 4 * q + lw;
        float v[4];
        #pragma unroll
        for (int j = 0; j < 4; ++j) v[j] = sB[e0 + j];
        #pragma unroll
        for (int p = 0; p < 8; ++p)
            #pragma unroll
            for (int j = 0; j < 4; ++j)
                v[j] += sScr[p][tl][e0 + j];

        // In-lane top-2 over 4 experts.
        float v1 = -INFINITY, v2 = -INFINITY;
        int i1 = 0, i2 = 0;
        #pragma unroll
        for (int j = 0; j < 4; ++j) {
            const float val = v[j];
            const int   e   = e0 + j;
            if (val > v1)      { v2 = v1; i2 = i1; v1 = val; i1 = e; }
            else if (val > v2) { v2 = val; i2 = e; }
        }
        // Butterfly merge across the 16 lanes of this token
        // (lex order: value desc, index asc == jax top_k tie semantics).
        #pragma unroll
        for (int s = 1; s <= 8; s <<= 1) {
            const float o1 = __shfl_xor(v1, s);
            const int  oi1 = __shfl_xor(i1, s);
            const float o2 = __shfl_xor(v2, s);
            const int  oi2 = __shfl_xor(i2, s);
            const bool b1 = (o1 > v1) || (o1 == v1 && oi1 < i1);
            if (b1) {
                const bool b2 = (v1 > o2) || (v1 == o2 && i1 < oi2);
                v2 = b2 ? v1 : o2;  i2 = b2 ? i1 : oi2;
                v1 = o1;            i1 = oi1;
            } else {
                const bool b2 = (o1 > v2) || (o1 == v2 && oi1 < i2);
                if (b2) { v2 = o1; i2 = oi1; }
            }
        }
        if (le == 0) {
            const int t = 32 * r + tl;
            const float ex = expf(v2 - v1);        // <= 1
            const float w1 = 1.f / (1.f + ex);
            rI1[t] = i1;  rI2[t] = i2;
            rW1[t] = w1;  rW2[t] = ex * w1;
        }
    }
    __syncthreads();

    // ---- Coalesced output: 64 tokens x 64 floats = 1024 float4, contiguous ----
    float4* O4 = (float4*)(Out + (size_t)tokBase * 64);
    #pragma unroll
    for (int idx = tid; idx < TPB * 64 / 4; idx += 512) {
        const int t  = idx >> 4;
        const int c0 = (idx & 15) << 2;
        const int i1 = rI1[t], i2 = rI2[t];
        const float w1 = rW1[t], w2 = rW2[t];
        float4 o;
        o.x = (c0 + 0 == i1) ? w1 : ((c0 + 0 == i2) ? w2 : 0.f);
        o.y = (c0 + 1 == i1) ? w1 : ((c0 + 1 == i2) ? w2 : 0.f);
        o.z = (c0 + 2 == i1) ? w1 : ((c0 + 2 == i2) ? w2 : 0.f);
        o.w = (c0 + 3 == i1) ? w1 : ((c0 + 3 == i2) ? w2 : 0.f);
        O4[idx] = o;
    }
}

extern "C" void kernel_launch(void* const* d_in, const int* in_sizes, int n_in,
                              void* d_out, int out_size, void* d_ws, size_t ws_size,
                              hipStream_t stream) {
    const float* X  = (const float*)d_in[0];   // [32768, 1024]
    const float* Wt = (const float*)d_in[1];   // [64, 1024]
    const float* Bv = (const float*)d_in[2];   // [64]
    float* Out = (float*)d_out;                // [32768, 64]

    const int tokens = 8 * 4096;               // 32768
    dim3 grid(tokens / TPB);                   // 512 blocks
    dim3 block(512);
    hipLaunchKernelGGL(router_kernel, grid, block, 0, stream, X, Wt, Bv, Out);
}

// Round 5
// 79.163 us; speedup vs baseline: 2.4972x; 1.0144x over previous
//
#include <hip/hip_runtime.h>
#include <hip/hip_bf16.h>
#include <math.h>

// Router: logits = X @ W^T + b ; top-2 over 64 experts; softmax over the 2; rest 0.
// X: [32768,1024] f32, W: [64,1024] f32, b: [64] f32, Out: [32768,64] f32.
//
// MFMA path: exact bf16 hi/lo split, 3-term product (hh + hl + lh); dropped
// lo*lo term ~2^-18 relative. Near-tie tokens (3rd logit within TAU of v2)
// are flagged and recomputed in pure fp32 by a rescue kernel (selection-exact).
//
// Kernels (same stream, serialized):
//   0) memsetAsync flag counter = 0
//   1) pack_w: W fp32 -> fragment-ordered bf16 hi/lo in d_ws (256 KB)
//   2) router_mfma: 512 blocks x 256 thr (4 waves); wave = 16 tokens x 64 experts;
//      K-loop 32 steps of mfma_f32_16x16x32_bf16, 12 MFMA/step; zero LDS;
//      2-deep register pipeline; epilogue top-2 via 16-lane butterfly, no LDS.
//   3) rescue: flagged tokens -> exact fp32 dot + 64-lane butterfly, overwrite row.
//
// A/B k-mapping: element j of lane l covers k = (l>>4)*8 + j. Both A (X, packed
// in-register) and B (W, pre-packed by pack_w) use the SAME mapping, so the MFMA
// k-sum is correct under any internal hardware k-permutation (bijection arg).
// C/D layout (m89-verified): col = lane&15, row = (lane>>4)*4 + reg.
//
// Requires ws_size >= 512 KB (cnt @0, list @256, Whi @256K, Wlo @384K).

typedef __attribute__((ext_vector_type(8))) short bf16x8;
typedef __attribute__((ext_vector_type(4))) float f32x4;

#define TOKENS 32768
#define DDIM   1024
#define NEXP   64
#define KSTEPS 32
#define TAU    1e-3f

#define WS_CNT_OFF   0
#define WS_LIST_OFF  256
#define WS_WHI_OFF   262144
#define WS_WLO_OFF   (262144 + 131072)

union FragU { bf16x8 v; unsigned int u[4]; };

__device__ inline unsigned int pk_bf16(float a, float b) {
    float2 f; f.x = a; f.y = b;
    __hip_bfloat162 h = __float22bfloat162_rn(f);
    union { __hip_bfloat162 h2; unsigned int u; } cv; cv.h2 = h;
    return cv.u;
}
__device__ inline float2 bf2f2(unsigned int u) {
    union { __hip_bfloat162 h2; unsigned int uu; } cv; cv.uu = u;
    return __bfloat1622float2(cv.h2);
}
__device__ inline void merge2(float& v1, int& i1, float& v2, int& i2,
                              float o1, int oi1, float o2, int oi2) {
    const bool b1 = (o1 > v1) || (o1 == v1 && oi1 < i1);
    if (b1) {
        const bool b2 = (v1 > o2) || (v1 == o2 && i1 < oi2);
        v2 = b2 ? v1 : o2;  i2 = b2 ? i1 : oi2;
        v1 = o1;            i1 = oi1;
    } else {
        const bool b2 = (o1 > v2) || (o1 == v2 && oi1 < i2);
        if (b2) { v2 = o1; i2 = oi1; }
    }
}

// ---- kernel 1: pack W into fragment-ordered bf16 hi/lo ----
__launch_bounds__(256)
__global__ void pack_w_kernel(const float* __restrict__ W,
                              unsigned int* __restrict__ Whi,
                              unsigned int* __restrict__ Wlo) {
    const int idx = blockIdx.x * 256 + threadIdx.x;     // 0..8191 = (s,n,l)
    const int l = idx & 63, n = (idx >> 6) & 3, s = idx >> 8;
    const int e  = n * 16 + (l & 15);
    const int k0 = s * 32 + (l >> 4) * 8;
    const float* p = W + e * DDIM + k0;
    const float4 a = *(const float4*)p;
    const float4 b = *(const float4*)(p + 4);
    const float f[8] = {a.x, a.y, a.z, a.w, b.x, b.y, b.z, b.w};
    unsigned int hu[4], lu[4];
    #pragma unroll
    for (int j = 0; j < 4; ++j) {
        const float x0 = f[2 * j], x1 = f[2 * j + 1];
        const unsigned int h = pk_bf16(x0, x1);
        const float2 hf = bf2f2(h);
        hu[j] = h;
        lu[j] = pk_bf16(x0 - hf.x, x1 - hf.y);
    }
    uint4 hv; hv.x = hu[0]; hv.y = hu[1]; hv.z = hu[2]; hv.w = hu[3];
    uint4 lv; lv.x = lu[0]; lv.y = lu[1]; lv.z = lu[2]; lv.w = lu[3];
    *(uint4*)(Whi + (size_t)idx * 4) = hv;
    *(uint4*)(Wlo + (size_t)idx * 4) = lv;
}

// ---- kernel 2: main MFMA router ----
__launch_bounds__(256, 2)
__global__ void router_mfma(const float* __restrict__ X,
                            const unsigned int* __restrict__ Whi,
                            const unsigned int* __restrict__ Wlo,
                            const float* __restrict__ Bv,
                            float* __restrict__ Out,
                            unsigned int* __restrict__ flagCnt,
                            int* __restrict__ flagList) {
    const int tid  = threadIdx.x;
    const int w    = tid >> 6;
    const int lane = tid & 63;
    const int rl   = lane & 15;       // A-row / B-col / C-col index
    const int kg   = lane >> 4;       // k-group
    const int tokBase = blockIdx.x * 64 + w * 16;

    const float* xp = X + (size_t)(tokBase + rl) * DDIM + kg * 8;
    const unsigned int* whp = Whi + (size_t)lane * 4;
    const unsigned int* wlp = Wlo + (size_t)lane * 4;

    f32x4 acc[4] = {f32x4{0,0,0,0}, f32x4{0,0,0,0}, f32x4{0,0,0,0}, f32x4{0,0,0,0}};

    float4 xaA, xbA, xaB, xbB;
    FragU bhA[4], blA[4], bhB[4], blB[4];

#define LDX(s, xa, xb) { const float* p_ = xp + (s) * 32; \
        xa = *(const float4*)p_; xb = *(const float4*)(p_ + 4); }
#define LDW(s, bh, bl) { \
        _Pragma("unroll") for (int n_ = 0; n_ < 4; ++n_) { \
            const size_t off_ = (size_t)(((s) * 4 + n_) * 64) * 4; \
            *(uint4*)&bh[n_].u[0] = *(const uint4*)(whp + off_); \
            *(uint4*)&bl[n_].u[0] = *(const uint4*)(wlp + off_); } }
#define CM(xa, xb, bh, bl) { \
        FragU ah_, al_; \
        const float fx_[8] = {xa.x, xa.y, xa.z, xa.w, xb.x, xb.y, xb.z, xb.w}; \
        _Pragma("unroll") for (int j_ = 0; j_ < 4; ++j_) { \
            const unsigned int h_ = pk_bf16(fx_[2*j_], fx_[2*j_+1]); \
            const float2 hf_ = bf2f2(h_); \
            ah_.u[j_] = h_; \
            al_.u[j_] = pk_bf16(fx_[2*j_] - hf_.x, fx_[2*j_+1] - hf_.y); } \
        _Pragma("unroll") for (int n_ = 0; n_ < 4; ++n_) { \
            acc[n_] = __builtin_amdgcn_mfma_f32_16x16x32_bf16(ah_.v, bh[n_].v, acc[n_], 0, 0, 0); \
            acc[n_] = __builtin_amdgcn_mfma_f32_16x16x32_bf16(ah_.v, bl[n_].v, acc[n_], 0, 0, 0); \
            acc[n_] = __builtin_amdgcn_mfma_f32_16x16x32_bf16(al_.v, bh[n_].v, acc[n_], 0, 0, 0); } }

    LDX(0, xaA, xbA); LDW(0, bhA, blA);
    LDX(1, xaB, xbB); LDW(1, bhB, blB);
    #pragma unroll 1
    for (int s = 0; s < KSTEPS; s += 2) {
        CM(xaA, xbA, bhA, blA);
        if (s + 2 < KSTEPS) { LDX(s + 2, xaA, xbA); LDW(s + 2, bhA, blA); }
        CM(xaB, xbB, bhB, blB);
        if (s + 3 < KSTEPS) { LDX(s + 3, xaB, xbB); LDW(s + 3, bhB, blB); }
    }
#undef LDX
#undef LDW
#undef CM

    // ---- epilogue: bias + per-token top-2 (16-lane butterfly) + write ----
    float bv[4];
    #pragma unroll
    for (int n = 0; n < 4; ++n) bv[n] = Bv[n * 16 + rl];

    #pragma unroll
    for (int r = 0; r < 4; ++r) {
        float v[4];
        #pragma unroll
        for (int n = 0; n < 4; ++n) v[n] = acc[n][r] + bv[n];

        // in-lane top-2 over this lane's 4 experts (e = n*16 + rl)
        float v1 = -INFINITY, v2 = -INFINITY;
        int i1 = 0x7fffffff, i2 = 0x7fffffff;
        #pragma unroll
        for (int n = 0; n < 4; ++n) {
            const float val = v[n];
            const int   e   = n * 16 + rl;
            if (val > v1 || (val == v1 && e < i1)) { v2 = v1; i2 = i1; v1 = val; i1 = e; }
            else if (val > v2 || (val == v2 && e < i2)) { v2 = val; i2 = e; }
        }
        // butterfly across the 16 lanes of this k-group (lex: value desc, idx asc)
        #pragma unroll
        for (int st = 1; st <= 8; st <<= 1) {
            const float o1 = __shfl_xor(v1, st); const int oi1 = __shfl_xor(i1, st);
            const float o2 = __shfl_xor(v2, st); const int oi2 = __shfl_xor(i2, st);
            merge2(v1, i1, v2, i2, o1, oi1, o2, oi2);
        }
        // near-tie flag: any 3rd logit within TAU of v2?
        int cnt = 0;
        #pragma unroll
        for (int n = 0; n < 4; ++n) cnt += (v[n] > v2 - TAU) ? 1 : 0;
        cnt += __shfl_xor(cnt, 1);
        cnt += __shfl_xor(cnt, 2);
        cnt += __shfl_xor(cnt, 4);
        cnt += __shfl_xor(cnt, 8);

        const int T = tokBase + kg * 4 + r;
        if (rl == 0 && cnt > 2) {
            const unsigned int pos = atomicAdd(flagCnt, 1u);
            if (pos < TOKENS) flagList[pos] = T;
        }
        const float ex = expf(v2 - v1);      // <= 1
        const float w1 = 1.f / (1.f + ex);
        const float w2 = ex * w1;
        const int e0 = rl * 4;
        float4 o;
        o.x = (e0 + 0 == i1) ? w1 : ((e0 + 0 == i2) ? w2 : 0.f);
        o.y = (e0 + 1 == i1) ? w1 : ((e0 + 1 == i2) ? w2 : 0.f);
        o.z = (e0 + 2 == i1) ? w1 : ((e0 + 2 == i2) ? w2 : 0.f);
        o.w = (e0 + 3 == i1) ? w1 : ((e0 + 3 == i2) ? w2 : 0.f);
        *(float4*)(Out + (size_t)T * 64 + e0) = o;
    }
}

// ---- kernel 3: exact fp32 rescue for near-tie tokens ----
__launch_bounds__(64)
__global__ void rescue_kernel(const float* __restrict__ X,
                              const float* __restrict__ W,
                              const float* __restrict__ Bv,
                              float* __restrict__ Out,
                              const unsigned int* __restrict__ flagCnt,
                              const int* __restrict__ flagList) {
    __shared__ float sx[DDIM];
    const int lane = threadIdx.x;
    unsigned int n = *flagCnt;
    if (n > TOKENS) n = TOKENS;
    for (unsigned int i = blockIdx.x; i < n; i += gridDim.x) {
        const int t = flagList[i];
        __syncthreads();
        #pragma unroll
        for (int k = 0; k < 4; ++k)
            ((float4*)sx)[lane + 64 * k] =
                ((const float4*)(X + (size_t)t * DDIM))[lane + 64 * k];
        __syncthreads();
        float acc = Bv[lane];
        const float* wr = W + (size_t)lane * DDIM;
        #pragma unroll 4
        for (int d = 0; d < DDIM; d += 4) {
            const float4 wv = *(const float4*)(wr + d);
            acc = fmaf(sx[d + 0], wv.x, acc);
            acc = fmaf(sx[d + 1], wv.y, acc);
            acc = fmaf(sx[d + 2], wv.z, acc);
            acc = fmaf(sx[d + 3], wv.w, acc);
        }
        float v1 = acc, v2 = -INFINITY;
        int i1 = lane, i2 = 0x7fffffff;
        #pragma unroll
        for (int st = 1; st <= 32; st <<= 1) {
            const float o1 = __shfl_xor(v1, st); const int oi1 = __shfl_xor(i1, st);
            const float o2 = __shfl_xor(v2, st); const int oi2 = __shfl_xor(i2, st);
            merge2(v1, i1, v2, i2, o1, oi1, o2, oi2);
        }
        const float ex = expf(v2 - v1);
        const float w1 = 1.f / (1.f + ex);
        const float w2 = ex * w1;
        Out[(size_t)t * 64 + lane] = (lane == i1) ? w1 : ((lane == i2) ? w2 : 0.f);
    }
}

extern "C" void kernel_launch(void* const* d_in, const int* in_sizes, int n_in,
                              void* d_out, int out_size, void* d_ws, size_t ws_size,
                              hipStream_t stream) {
    const float* X  = (const float*)d_in[0];   // [32768, 1024]
    const float* W  = (const float*)d_in[1];   // [64, 1024]
    const float* Bv = (const float*)d_in[2];   // [64]
    float* Out = (float*)d_out;                // [32768, 64]

    unsigned char* ws = (unsigned char*)d_ws;
    unsigned int* cnt  = (unsigned int*)(ws + WS_CNT_OFF);
    int*          list = (int*)(ws + WS_LIST_OFF);
    unsigned int* Whi  = (unsigned int*)(ws + WS_WHI_OFF);
    unsigned int* Wlo  = (unsigned int*)(ws + WS_WLO_OFF);

    hipMemsetAsync(cnt, 0, 4, stream);
    hipLaunchKernelGGL(pack_w_kernel, dim3(32), dim3(256), 0, stream, W, Whi, Wlo);
    hipLaunchKernelGGL(router_mfma, dim3(TOKENS / 64), dim3(256), 0, stream,
                       X, Whi, Wlo, Bv, Out, cnt, list);
    hipLaunchKernelGGL(rescue_kernel, dim3(512), dim3(64), 0, stream,
                       X, W, Bv, Out, cnt, list);
}